// Round 11
// baseline (219.456 us; speedup 1.0000x reference)
//
#include <hip/hip_runtime.h>
#include <cstddef>

// BoardModel: B=16384. out = [xf(32), a_mean(32), b2(32)] per sample, then board (3,22,12).
// MHA is degenerate (kv len 1 -> softmax==1): a_mean = out_proj(in_proj[64:96] @ b2 + b).
//
// R11: wave-autonomous (one wave = one sample, ZERO __syncthreads) with all
// cross-launch-sensitive accesses on proven patterns:
//   - d_ws carries ONLY the cb border table; consumed by start-of-kernel staging
//     into LDS (R6-R9-proven). Staged per-wave redundantly (identical values) so
//     no block barrier is needed.  [R10 read d_ws with per-lane vector loads deep
//     in the kernel and diverged post-timing under the poisoned-ws replays.]
//   - conv1 dense weights: w1 input buffer, wave-uniform index -> SGPR (R7/R8).
//   - conv2 weights: w2 input buffer direct, per-lane (L1-hot, 2.4KB total).
//   - tail GEMV weights: input buffers direct, per-lane pk-FMA (R9/R10).
//   - __threadfence_block() at every wave-phase boundary (lgkmcnt drain, ~free)
//     to pin LDS ordering at compiler and HW level.
//   - NO min-waves bound (R1/R4 spill pathology). LDS 18.8KB -> 8 blocks/CU.

typedef float f32x2 __attribute__((ext_vector_type(2)));

#define BATCH 16384
#define SPB   4
#define NBLK  (BATCH / SPB)
#define RS    18
#define P1OFF  432          // P1: [o*61 + p], p<60 (366 floats)
#define PCSOFF 800          // 16 ints
#define SS2    816          // floats per wave; tail overlays SBE: C2 192 @0, P2 48 @192,
                            // C3 64 @240, B2 32 @304, V 32 @336.

// ---- precompute: cb[p*6+o] = sum over window taps hitting border-one cells,
//      summed over all 3 input channels (border is 1.0 in every channel). ----
__global__ __launch_bounds__(256)
void cborder_kernel(const float* __restrict__ w1, float* __restrict__ cb)
{
  int i = blockIdx.x * 256 + threadIdx.x;
  if (i >= 1584) return;
  int p = i / 6, o = i - p * 6;
  int y0 = p / 12, x0 = p - y0 * 12;
  float acc = 0.f;
#pragma unroll
  for (int dy = 0; dy < 5; ++dy)
#pragma unroll
    for (int dx = 0; dx < 5; ++dx) {
      int pr = y0 + dy - 2, pc = x0 + dx - 2;
      if (pr >= 0 && pr < 22 && pc >= 0 && pc < 12 &&
          (pr == 21 || pc == 0 || pc == 11)) {
        int k = dy * 5 + dx;
        acc += w1[(o * 3 + 0) * 25 + k] + w1[(o * 3 + 1) * 25 + k]
             + w1[(o * 3 + 2) * 25 + k];
      }
    }
  cb[i] = acc;
}

__global__ __launch_bounds__(256)
void board_model_kernel(const int* __restrict__ t,           // (B,232)
                        const int* __restrict__ piece_table, // (8,4,4,4)
                        const float* __restrict__ w1, const float* __restrict__ b1,
                        const float* __restrict__ w2, const float* __restrict__ b2w,
                        const float* __restrict__ w3, const float* __restrict__ b3,
                        const float* __restrict__ wf1, const float* __restrict__ bf1,
                        const float* __restrict__ fcw, const float* __restrict__ fcb,
                        const float* __restrict__ ipw, const float* __restrict__ ipb,
                        const float* __restrict__ opw, const float* __restrict__ opb,
                        const float* __restrict__ cbg,        // (264,6) border contrib
                        float* __restrict__ out,              // (B,96)
                        float* __restrict__ out_board)        // (B,3,22,12)
{
  __shared__ __align__(16) float scr[SPB * SS2];
  __shared__ float cbL[1440];    // conv cells rows 0..19

  const int tid  = threadIdx.x;
  const int lane = tid & 63;
  const int wv   = tid >> 6;          // wave id == sample slot (autonomous)
  const int s    = blockIdx.x * SPB + wv;

  float* W   = &scr[wv * SS2];
  int*   pcs = (int*)&scr[wv * SS2 + PCSOFF];
  const int* tr = t + (size_t)s * 232;

  // ---- 0. stage cb -> LDS, PER-WAVE redundant (identical values; no block barrier;
  //         each wave's own writes precede its reads in program order) ----
  for (int i = lane; i < 1440; i += 64) cbL[i] = cbg[i];

  // ---- 1. SBE ch0 build + piece list (per-wave LDS only) ----
  {
    float4* W4 = (float4*)W;
    for (int i = lane; i < 108; i += 64) W4[i] = float4{0.f, 0.f, 0.f, 0.f};

    for (int i = lane; i < 210; i += 64) {
      int r = i / 10, b = i - r * 10;
      W[(r + 2) * RS + b + 5] = (float)tr[22 + i];
    }

    if (lane < 4) {
      const int* pt = piece_table + (tr[8] * 4 + tr[4]) * 16;
      int sel = -1, n1 = 0;
#pragma unroll
      for (int j = 0; j < 16; ++j) { if (pt[j]) { if (n1 == lane) sel = j; ++n1; } }
      if (sel < 0) {
        int n0 = 0, want = lane - n1;
#pragma unroll
        for (int j = 0; j < 16; ++j) if (!pt[j]) { if (n0 == want) { sel = j; break; } ++n0; }
      }
      int cy = sel >> 2, cx = sel & 3;
      int x  = cx + tr[1] - 2;
      int y  = cy + tr[2];
      int ny = y + tr[3];
      bool mask = (y >= 0) && (ny >= 0);
      bool xok  = (x >= 0) && (x < 10);
      bool v1 = mask && xok && (y < 21);
      bool v2 = mask && xok && (ny < 21);
      pcs[2 * lane + 0]       = v1 ? y  : -100;
      pcs[2 * lane + 1]       = x + 1;
      pcs[2 * (lane + 4)]     = v2 ? ny : -100;
      pcs[2 * (lane + 4) + 1] = x + 1;
    }
  }
  __threadfence_block();
  __builtin_amdgcn_wave_barrier();

  // ---- 2. board output stores (fire-and-forget; drain under conv1) ----
  {
    float* ob = out_board + (size_t)s * 792;
    for (int v = lane; v < 198; v += 64) {
      int j0 = v * 4;
      int ch = j0 / 264, rem = j0 - ch * 264;
      int r = rem / 12, c = rem - r * 12;
      float val[4];
      if (ch == 0) {
#pragma unroll
        for (int d = 0; d < 4; ++d) {
          int cd = c + d;
          val[d] = (r == 21 || cd == 0 || cd == 11) ? 1.f
                 : W[(r + 2) * RS + cd + 4];
        }
      } else {
#pragma unroll
        for (int d = 0; d < 4; ++d) {
          int cd = c + d;
          val[d] = (r == 21 || cd == 0 || cd == 11) ? 1.f : 0.f;
        }
#pragma unroll
        for (int e = 0; e < 4; ++e) {
          int pr = pcs[2 * ((ch - 1) * 4 + e)];
          int pc = pcs[2 * ((ch - 1) * 4 + e) + 1];
          if (pr == r && (unsigned)(pc - c) < 4u) val[pc - c] = 1.f;
        }
      }
      *(float4*)(ob + j0) = float4{val[0], val[1], val[2], val[3]};
    }
  }

  // ---- 3. conv1+relu+pool1 (lanes 0..59); dense w1 uniform -> SGPR ----
  if (lane < 60) {
    int p = lane;
    int r = p / 6, c = p - r * 6;
    float acc[2][2][6];
#pragma unroll
    for (int i = 0; i < 2; ++i)
#pragma unroll
      for (int j = 0; j < 2; ++j) {
        int pcell = (2 * r + i) * 12 + (2 * c + j);
#pragma unroll
        for (int o = 0; o < 6; ++o)
          acc[i][j][o] = b1[o] + cbL[pcell * 6 + o];
      }

    // dense ch0 rolling-row (600 FMA); weights via w1 uniform index -> SGPR
    {
      const float* base = W + (2 * r) * RS + (2 * c + 2);
#pragma unroll
      for (int u = 0; u < 6; ++u) {
        float2 a0 = *(const float2*)(base + u * RS);
        float2 a1 = *(const float2*)(base + u * RS + 2);
        float2 a2 = *(const float2*)(base + u * RS + 4);
        float rv[6] = {a0.x, a0.y, a1.x, a1.y, a2.x, a2.y};
#pragma unroll
        for (int i = 0; i < 2; ++i) {
          if (u - i < 0 || u - i > 4) continue;   // folds at compile time
          const int ky = u - i;
#pragma unroll
          for (int j = 0; j < 2; ++j)
#pragma unroll
            for (int kx = 0; kx < 5; ++kx) {
              float xv = rv[j + kx];
#pragma unroll
              for (int o = 0; o < 6; ++o)
                acc[i][j][o] += xv * w1[o * 75 + ky * 5 + kx];   // uniform -> SGPR
            }
        }
      }
    }

    // sparse piece taps (value==1 -> add weight); per-lane w1 reads (L1-hot)
#pragma unroll
    for (int e = 0; e < 8; ++e) {
      int pr = pcs[2 * e];
      if (pr < 0) continue;
      int pc = pcs[2 * e + 1];
      int chm = e >> 2;                       // 0 -> ch1, 1 -> ch2
      int dyb = pr + 2 - 2 * r;
      int dxb = pc + 2 - 2 * c;
      if (dyb < 0 || dyb > 5 || dxb < 0 || dxb > 5) continue;
#pragma unroll
      for (int i = 0; i < 2; ++i) {
        int dy = dyb - i;
        if ((unsigned)dy >= 5u) continue;
#pragma unroll
        for (int j = 0; j < 2; ++j) {
          int dx = dxb - j;
          if ((unsigned)dx >= 5u) continue;
#pragma unroll
          for (int o = 0; o < 6; ++o)
            acc[i][j][o] += w1[(o * 3 + 1 + chm) * 25 + dy * 5 + dx];
        }
      }
    }

    float* P1q = W + P1OFF;
#pragma unroll
    for (int o = 0; o < 6; ++o) {
      float v = fmaxf(acc[0][0][o], 0.f) + fmaxf(acc[0][1][o], 0.f)
              + fmaxf(acc[1][0][o], 0.f) + fmaxf(acc[1][1][o], 0.f);
      P1q[o * 61 + p] = 0.25f * v;
    }
  }
  __threadfence_block();
  __builtin_amdgcn_wave_barrier();

  // ---- 4. conv2+relu, wave-local: lane=(oc,pq), 3 positions/lane ----
  {
    const int oc = lane >> 2;          // 0..15
    const int pq = lane & 3;           // 0..3
    const int r0 = pq >> 1, c0 = pq & 1;
    const float* P1q = W + P1OFF;
    float a3[3];
    float bv = b2w[oc];
    a3[0] = bv; a3[1] = bv; a3[2] = bv;
    for (int ic = 0; ic < 6; ++ic) {
      float wch[25];
#pragma unroll
      for (int j = 0; j < 25; ++j)
        wch[j] = w2[oc * 150 + ic * 25 + j];     // input buffer direct, L1-hot
#pragma unroll
      for (int u = 0; u < 9; ++u) {              // window rows shared by 3 positions
        float xv[5];
#pragma unroll
        for (int kc = 0; kc < 5; ++kc)
          xv[kc] = P1q[ic * 61 + (r0 + u) * 6 + c0 + kc];   // 16-way broadcast
        if (u <= 4) {
#pragma unroll
          for (int kc = 0; kc < 5; ++kc) a3[0] += xv[kc] * wch[u * 5 + kc];
        }
        if (u >= 2 && u <= 6) {
#pragma unroll
          for (int kc = 0; kc < 5; ++kc) a3[1] += xv[kc] * wch[(u - 2) * 5 + kc];
        }
        if (u >= 4) {
#pragma unroll
          for (int kc = 0; kc < 5; ++kc) a3[2] += xv[kc] * wch[(u - 4) * 5 + kc];
        }
      }
    }
    // C2 overlays SBE (wave program order: board stores/conv1 reads precede)
    W[oc * 12 + pq]     = fmaxf(a3[0], 0.f);
    W[oc * 12 + pq + 4] = fmaxf(a3[1], 0.f);
    W[oc * 12 + pq + 8] = fmaxf(a3[2], 0.f);
  }
  __threadfence_block();
  __builtin_amdgcn_wave_barrier();

  // ---- 5. per-wave tail ----
  {
    float* S = W;

    if (lane < 48) {
      int o = lane / 3, pr = lane - o * 3;
      float v = 0.25f * (S[o * 12 + 4 * pr] + S[o * 12 + 4 * pr + 1]
                       + S[o * 12 + 4 * pr + 2] + S[o * 12 + 4 * pr + 3]);
      S[192 + lane] = v;
    }
    __threadfence_block();
    __builtin_amdgcn_wave_barrier();

    // conv3+relu: lane = out channel; K pairs (per-lane w3 direct, L1-hot)
    {
      int o = lane;
      const f32x2* w3r = (const f32x2*)(w3 + o * 48);
      f32x2 accp = f32x2{b3[o], 0.f};
#pragma unroll
      for (int k2 = 0; k2 < 24; ++k2)
        accp += *(const f32x2*)(S + 192 + 2 * k2) * w3r[k2];
      S[240 + o] = fmaxf(accp.x + accp.y, 0.f);
    }
    __threadfence_block();
    __builtin_amdgcn_wave_barrier();

    // fc1+relu: j=lane&31, k-half split + pk + shfl combine
    {
      int j = lane & 31, h = lane >> 5;
      const f32x2* wr = (const f32x2*)(wf1 + j * 64 + 32 * h);
      f32x2 accp = f32x2{0.f, 0.f};
#pragma unroll
      for (int k2 = 0; k2 < 16; ++k2)
        accp += *(const f32x2*)(S + 240 + 32 * h + 2 * k2) * wr[k2];
      float part = accp.x + accp.y;
      part += __shfl_xor(part, 32, 64);
      if (h == 0) {
        float acc = fmaxf(bf1[j] + part, 0.f);
        S[304 + j] = acc;
        out[(size_t)s * 96 + 64 + j] = acc;
      }
    }
    __threadfence_block();
    __builtin_amdgcn_wave_barrier();

    // lanes 0..31: v = ipw[64:96] @ b2 + ipb ; lanes 32..63: xf (independent)
    {
      int j = lane & 31;
      if (lane < 32) {
        const f32x2* wr = (const f32x2*)(ipw + (64 + j) * 32);
        f32x2 accp = f32x2{ipb[64 + j], 0.f};
#pragma unroll
        for (int k2 = 0; k2 < 16; ++k2)
          accp += *(const f32x2*)(S + 304 + 2 * k2) * wr[k2];
        S[336 + j] = accp.x + accp.y;
      } else {
        const f32x2* wr = (const f32x2*)(fcw + j * 8);
        f32x2 accp = f32x2{fcb[j], 0.f};
#pragma unroll
        for (int k2 = 0; k2 < 4; ++k2) {
          f32x2 tv = f32x2{(float)tr[2 * k2], (float)tr[2 * k2 + 1]};
          accp += tv * wr[k2];
        }
        out[(size_t)s * 96 + j] = fmaxf(accp.x + accp.y, 0.f);
      }
    }
    __threadfence_block();
    __builtin_amdgcn_wave_barrier();

    // a_mean = opw @ v + opb
    if (lane < 32) {
      int j = lane;
      const f32x2* wr = (const f32x2*)(opw + j * 32);
      f32x2 accp = f32x2{opb[j], 0.f};
#pragma unroll
      for (int k2 = 0; k2 < 16; ++k2)
        accp += *(const f32x2*)(S + 336 + 2 * k2) * wr[k2];
      out[(size_t)s * 96 + 32 + j] = accp.x + accp.y;
    }
  }
}

extern "C" void kernel_launch(void* const* d_in, const int* in_sizes, int n_in,
                              void* d_out, int out_size, void* d_ws, size_t ws_size,
                              hipStream_t stream) {
  const int*   t   = (const int*)d_in[0];
  const int*   pt  = (const int*)d_in[1];
  const float* w1  = (const float*)d_in[2];
  const float* b1  = (const float*)d_in[3];
  const float* w2  = (const float*)d_in[4];
  const float* b2w = (const float*)d_in[5];
  const float* w3  = (const float*)d_in[6];
  const float* b3  = (const float*)d_in[7];
  const float* wf1 = (const float*)d_in[8];
  const float* bf1 = (const float*)d_in[9];
  const float* fcw = (const float*)d_in[10];
  const float* fcb = (const float*)d_in[11];
  // d_in[12] = emb : dead (softmax over singleton axis == 1)
  const float* ipw = (const float*)d_in[13];
  const float* ipb = (const float*)d_in[14];
  const float* opw = (const float*)d_in[15];
  const float* opb = (const float*)d_in[16];

  float* out       = (float*)d_out;
  float* out_board = out + (size_t)BATCH * 96;
  float* cbg       = (float*)d_ws;     // 1584 floats

  hipLaunchKernelGGL(cborder_kernel, dim3(7), dim3(256), 0, stream, w1, cbg);
  hipLaunchKernelGGL(board_model_kernel, dim3(NBLK), dim3(256), 0, stream,
                     t, pt, w1, b1, w2, b2w, w3, b3, wf1, bf1, fcw, fcb,
                     ipw, ipb, opw, opb, cbg, out, out_board);
}

// Round 12
// 214.695 us; speedup vs baseline: 1.0222x; 1.0222x over previous
//
#include <hip/hip_runtime.h>
#include <cstddef>

// BoardModel: B=16384. out = [xf(32), a_mean(32), b2(32)] per sample, then board (3,22,12).
// MHA is degenerate (kv len 1 -> softmax==1): a_mean = out_proj(in_proj[64:96] @ b2 + b).
//
// R12: HALF-WAVE PER SAMPLE (8 samples / 256-thr block), 2x ILP per wave:
//  - conv1: lane (l<30) computes two adjacent pool positions (2l, 2l+1): shared
//    window rows (24 b64 / 2 positions), 2 independent pk-acc chains.
//  - conv1 result held in REGISTERS across a wave_barrier, then written as P1
//    OVERLAYING the dead SBE region -> SS2 = 464 floats; LDS 20.6KB -> 7 blocks/CU.
//  - conv2: lane = (oc=l>>1, rowblock=l&1); column-pair pk (b64 input pairs);
//    outputs stay in registers; pool2 via one shfl_xor(1); C2 never hits LDS.
//  - tail: all 32 lanes per sample (conv3 2oc/lane, fc1/v/amean/xf 1/lane), pk.
//  - d_ws access rules (R9/R10/R11 evidence): top-of-kernel staging loads (cbL)
//    and wave-uniform scalar (w1p2) ONLY. Lane-dependent weights from input
//    buffers (w1 taps, w2, w3, wf1, ipw, opw, fcw) - all R11-proven.
//  - ONE __syncthreads (after cbL staging + board build). NO min-waves bound.

typedef float f32x2 __attribute__((ext_vector_type(2)));

#define BATCH 16384
#define SPB   8
#define NBLK  (BATCH / SPB)
#define RS    18
#define SS2    464          // SBE 432 @0 (P1 [o*62+p] overlays @0 after conv1;
                            // then P2 48 @0, C3 64 @64, B2 32 @144, V 32 @176), pcs @448
#define P1S    62           // P1 channel stride (even: b64-aligned rows)
// d_ws floats: cb 1584 @0, w1p 150 @1584
#define WS_W1P 1584

__global__ __launch_bounds__(256)
void precomp_kernel(const float* __restrict__ w1, float* __restrict__ ws)
{
  int i = blockIdx.x * 256 + threadIdx.x;
  if (i < 1584) {
    int p = i / 6, o = i - p * 6;
    int y0 = p / 12, x0 = p - y0 * 12;
    float acc = 0.f;
#pragma unroll
    for (int dy = 0; dy < 5; ++dy)
#pragma unroll
      for (int dx = 0; dx < 5; ++dx) {
        int pr = y0 + dy - 2, pc = x0 + dx - 2;
        if (pr >= 0 && pr < 22 && pc >= 0 && pc < 12 &&
            (pr == 21 || pc == 0 || pc == 11)) {
          int k = dy * 5 + dx;
          acc += w1[(o * 3 + 0) * 25 + k] + w1[(o * 3 + 1) * 25 + k]
               + w1[(o * 3 + 2) * 25 + k];
        }
      }
    ws[i] = acc;
  } else if (i < 1734) {
    int j = i - 1584;                 // w1p[tap*6+o] = w1 ch0 (tap-major for pk pairs)
    int tap = j / 6, o = j - tap * 6;
    ws[i] = w1[o * 75 + tap];
  }
}

__global__ __launch_bounds__(256)
void board_model_kernel(const int* __restrict__ t,           // (B,232)
                        const int* __restrict__ piece_table, // (8,4,4,4)
                        const float* __restrict__ w1, const float* __restrict__ b1,
                        const float* __restrict__ w2, const float* __restrict__ b2w,
                        const float* __restrict__ w3, const float* __restrict__ b3,
                        const float* __restrict__ wf1, const float* __restrict__ bf1,
                        const float* __restrict__ fcw, const float* __restrict__ fcb,
                        const float* __restrict__ ipw, const float* __restrict__ ipb,
                        const float* __restrict__ opw, const float* __restrict__ opb,
                        const float* __restrict__ ws,         // cb | w1p
                        float* __restrict__ out,              // (B,96)
                        float* __restrict__ out_board)        // (B,3,22,12)
{
  __shared__ __align__(16) float scr[SPB * SS2];
  __shared__ float cbL[1440];

  const int tid = threadIdx.x;
  const int l   = tid & 31;          // lane within half-wave
  const int u   = tid >> 5;          // half-wave id == sample slot (0..7)
  const int s   = blockIdx.x * SPB + u;

  const f32x2* w1p2 = (const f32x2*)(ws + WS_W1P);   // [tap*3+o2], uniform -> SGPR

  float* W   = &scr[u * SS2];
  int*   pcs = (int*)&scr[u * SS2 + 448];
  const int* tr = t + (size_t)s * 232;

  // ---- stage cb -> LDS (block-cooperative, top-of-kernel: proven pattern) ----
  for (int i = tid; i < 1440; i += 256) cbL[i] = ws[i];

  // ---- build SBE ch0 + piece list (half-wave local) ----
  {
    float4* W4 = (float4*)W;
    for (int i = l; i < 108; i += 32) W4[i] = float4{0.f, 0.f, 0.f, 0.f};

    for (int i = l; i < 210; i += 32) {
      int r = i / 10, b = i - r * 10;
      W[(r + 2) * RS + b + 5] = (float)tr[22 + i];
    }

    if (l < 4) {
      const int* pt = piece_table + (tr[8] * 4 + tr[4]) * 16;
      int sel = -1, n1 = 0;
#pragma unroll
      for (int j = 0; j < 16; ++j) { if (pt[j]) { if (n1 == l) sel = j; ++n1; } }
      if (sel < 0) {
        int n0 = 0, want = l - n1;
#pragma unroll
        for (int j = 0; j < 16; ++j) if (!pt[j]) { if (n0 == want) { sel = j; break; } ++n0; }
      }
      int cy = sel >> 2, cx = sel & 3;
      int x  = cx + tr[1] - 2;
      int y  = cy + tr[2];
      int ny = y + tr[3];
      bool mask = (y >= 0) && (ny >= 0);
      bool xok  = (x >= 0) && (x < 10);
      bool v1 = mask && xok && (y < 21);
      bool v2 = mask && xok && (ny < 21);
      pcs[2 * l + 0]       = v1 ? y  : -100;
      pcs[2 * l + 1]       = x + 1;
      pcs[2 * (l + 4)]     = v2 ? ny : -100;
      pcs[2 * (l + 4) + 1] = x + 1;
    }
  }
  __syncthreads();   // cbL visible to all; builds done (the ONLY block barrier)

  // ---- board output stores (fire-and-forget; drain under conv1) ----
  {
    float* ob = out_board + (size_t)s * 792;
    for (int v = l; v < 198; v += 32) {
      int j0 = v * 4;
      int ch = j0 / 264, rem = j0 - ch * 264;
      int r = rem / 12, c = rem - r * 12;
      float val[4];
      if (ch == 0) {
#pragma unroll
        for (int d = 0; d < 4; ++d) {
          int cd = c + d;
          val[d] = (r == 21 || cd == 0 || cd == 11) ? 1.f
                 : W[(r + 2) * RS + cd + 4];
        }
      } else {
#pragma unroll
        for (int d = 0; d < 4; ++d) {
          int cd = c + d;
          val[d] = (r == 21 || cd == 0 || cd == 11) ? 1.f : 0.f;
        }
#pragma unroll
        for (int e = 0; e < 4; ++e) {
          int pr = pcs[2 * ((ch - 1) * 4 + e)];
          int pc = pcs[2 * ((ch - 1) * 4 + e) + 1];
          if (pr == r && (unsigned)(pc - c) < 4u) val[pc - c] = 1.f;
        }
      }
      *(float4*)(ob + j0) = float4{val[0], val[1], val[2], val[3]};
    }
  }

  // ---- conv1+relu+pool1: lane l<30 -> positions 2l, 2l+1 (same row, adj cols) ----
  float p1v[2][6];                    // pooled outputs held in registers
  {
    const int r  = (2 * l) / 6;
    const int ca = 2 * l - r * 6;     // 0,2,4
    f32x2 acc2[2][2][2][3];           // [pos][i][j][o2]
    if (l < 30) {
#pragma unroll
      for (int pos = 0; pos < 2; ++pos)
#pragma unroll
        for (int i = 0; i < 2; ++i)
#pragma unroll
          for (int j = 0; j < 2; ++j) {
            int pcell = (2 * r + i) * 12 + (2 * (ca + pos) + j);
#pragma unroll
            for (int o2 = 0; o2 < 3; ++o2) {
              f32x2 cb2 = *(const f32x2*)&cbL[pcell * 6 + 2 * o2];
              acc2[pos][i][j][o2] = f32x2{b1[2 * o2] + cb2.x, b1[2 * o2 + 1] + cb2.y};
            }
          }

      // dense ch0: shared rows, 8-float window, 600 pk (uniform w1p2 -> SGPR pairs)
      const float* base = W + (2 * r) * RS + (2 * ca + 2);
#pragma unroll
      for (int uu = 0; uu < 6; ++uu) {
        float2 a0 = *(const float2*)(base + uu * RS);
        float2 a1 = *(const float2*)(base + uu * RS + 2);
        float2 a2 = *(const float2*)(base + uu * RS + 4);
        float2 a3 = *(const float2*)(base + uu * RS + 6);
        float rv[8] = {a0.x, a0.y, a1.x, a1.y, a2.x, a2.y, a3.x, a3.y};
#pragma unroll
        for (int i = 0; i < 2; ++i) {
          if (uu - i < 0 || uu - i > 4) continue;   // folds at compile time
          const int ky = uu - i;
#pragma unroll
          for (int kx = 0; kx < 5; ++kx) {
            const int tap = ky * 5 + kx;
#pragma unroll
            for (int pos = 0; pos < 2; ++pos)
#pragma unroll
              for (int j = 0; j < 2; ++j) {
                float xv = rv[2 * pos + j + kx];
#pragma unroll
                for (int o2 = 0; o2 < 3; ++o2)
                  acc2[pos][i][j][o2] += w1p2[tap * 3 + o2] * f32x2{xv, xv};
              }
          }
        }
      }

      // sparse piece taps: per-lane w1 input-buffer reads (L1-hot)
#pragma unroll
      for (int e = 0; e < 8; ++e) {
        int pr = pcs[2 * e];
        if (pr < 0) continue;
        int pc = pcs[2 * e + 1];
        int chm = e >> 2;
#pragma unroll
        for (int pos = 0; pos < 2; ++pos) {
          int dyb = pr + 2 - 2 * r;
          int dxb = pc + 2 - 2 * (ca + pos);
          if (dyb < 0 || dyb > 5 || dxb < 0 || dxb > 5) continue;
#pragma unroll
          for (int i = 0; i < 2; ++i) {
            int dy = dyb - i;
            if ((unsigned)dy >= 5u) continue;
#pragma unroll
            for (int j = 0; j < 2; ++j) {
              int dx = dxb - j;
              if ((unsigned)dx >= 5u) continue;
#pragma unroll
              for (int o = 0; o < 6; ++o)
                acc2[pos][i][j][o >> 1][o & 1] += w1[(o * 3 + 1 + chm) * 25 + dy * 5 + dx];
            }
          }
        }
      }

#pragma unroll
      for (int pos = 0; pos < 2; ++pos)
#pragma unroll
        for (int o = 0; o < 6; ++o) {
          int o2 = o >> 1, ob = o & 1;
          p1v[pos][o] = 0.25f * (fmaxf(acc2[pos][0][0][o2][ob], 0.f)
                               + fmaxf(acc2[pos][0][1][o2][ob], 0.f)
                               + fmaxf(acc2[pos][1][0][o2][ob], 0.f)
                               + fmaxf(acc2[pos][1][1][o2][ob], 0.f));
        }
    }
  }
  __threadfence_block();
  __builtin_amdgcn_wave_barrier();    // SBE reads (conv1/board) done -> P1 may overlay

  if (l < 30) {
#pragma unroll
    for (int o = 0; o < 6; ++o)
      *(f32x2*)&W[o * P1S + 2 * l] = f32x2{p1v[0][o], p1v[1][o]};  // P1 overlays SBE
  }
  __threadfence_block();
  __builtin_amdgcn_wave_barrier();

  // ---- conv2+relu (+pool2 in regs): lane = (oc=l>>1, rb=l&1); col-pair pk ----
  float p2a = 0.f, p2b = 0.f;         // this lane's pool2 outputs (see below)
  {
    const int oc = l >> 1;
    const int rb = l & 1;             // rows 3rb .. 3rb+2
    f32x2 a[3];
    float bv = b2w[oc];
    a[0] = f32x2{bv, bv}; a[1] = f32x2{bv, bv}; a[2] = f32x2{bv, bv};
    for (int ic = 0; ic < 6; ++ic) {
      float wch[25];
#pragma unroll
      for (int j = 0; j < 25; ++j)
        wch[j] = w2[oc * 150 + ic * 25 + j];      // input buffer, L1-hot
      const float* P1r = W + ic * P1S + (3 * rb) * 6;
#pragma unroll
      for (int uu = 0; uu < 7; ++uu) {            // window rows shared by 3 rows
        float2 b0 = *(const float2*)(P1r + uu * 6);
        float2 b1v = *(const float2*)(P1r + uu * 6 + 2);
        float2 b2v = *(const float2*)(P1r + uu * 6 + 4);
        float rv[6] = {b0.x, b0.y, b1v.x, b1v.y, b2v.x, b2v.y};
#pragma unroll
        for (int ri = 0; ri < 3; ++ri) {
          int ky = uu - ri;
          if (ky < 0 || ky > 4) continue;         // folds at compile time
#pragma unroll
          for (int kc = 0; kc < 5; ++kc)
            a[ri] += f32x2{rv[kc], rv[kc + 1]} * f32x2{wch[ky * 5 + kc], wch[ky * 5 + kc]};
        }
      }
    }
    // relu + pool2 in registers: rows 3rb+ri, pr groups (0,1),(2,3),(4,5)
    float rs[3];
#pragma unroll
    for (int ri = 0; ri < 3; ++ri)
      rs[ri] = fmaxf(a[ri].x, 0.f) + fmaxf(a[ri].y, 0.f);
    // rb=0: rows 0,1,2 -> pr0 = rs0+rs1; partial pr1 = rs2
    // rb=1: rows 3,4,5 -> partial pr1 = rs0; pr2 = rs1+rs2
    float partner = rs[rb == 0 ? 2 : 0];
    float other = __shfl_xor(partner, 1, 64);     // pairs (2m,2m+1) stay in half
    p2a = (rb == 0) ? 0.25f * (rs[0] + rs[1]) : 0.25f * (rs[0] + other);
    p2b = (rb == 0) ? 0.f                     : 0.25f * (rs[1] + rs[2]);
    // lane rb=0 also needs pr1 = 0.25*(rs2 + other(rb1.rs0)):
    if (rb == 0) p2b = 0.25f * (rs[2] + other);
  }
  __threadfence_block();
  __builtin_amdgcn_wave_barrier();    // P1 reads done -> P2 may overlay @0

  {
    const int oc = l >> 1;
    const int rb = l & 1;
    if (rb == 0) {
      W[oc * 3 + 0] = p2a;            // pr0
      W[oc * 3 + 1] = p2b;            // pr1
    } else {
      W[oc * 3 + 2] = p2b;            // pr2
    }
  }
  __threadfence_block();
  __builtin_amdgcn_wave_barrier();

  // ---- tail: 32 lanes per sample ----
  {
    float* S = W;

    // conv3+relu: lane -> oc = l, l+32 (2 outputs), pk over K=48 (P2 @0)
#pragma unroll
    for (int half = 0; half < 2; ++half) {
      int o = l + 32 * half;
      const f32x2* w3r = (const f32x2*)(w3 + o * 48);
      f32x2 accp = f32x2{b3[o], 0.f};
#pragma unroll
      for (int k2 = 0; k2 < 24; ++k2)
        accp += *(const f32x2*)(S + 2 * k2) * w3r[k2];
      S[64 + o] = fmaxf(accp.x + accp.y, 0.f);
    }
    __threadfence_block();
    __builtin_amdgcn_wave_barrier();

    // fc1+relu: j = l, K=64 (C3 @64)
    {
      int j = l;
      const f32x2* wr = (const f32x2*)(wf1 + j * 64);
      f32x2 accp = f32x2{bf1[j], 0.f};
#pragma unroll
      for (int k2 = 0; k2 < 32; ++k2)
        accp += *(const f32x2*)(S + 64 + 2 * k2) * wr[k2];
      float acc = fmaxf(accp.x + accp.y, 0.f);
      S[144 + j] = acc;
      out[(size_t)s * 96 + 64 + j] = acc;
    }
    __threadfence_block();
    __builtin_amdgcn_wave_barrier();

    // v = ipw[64:96] @ b2 + ipb (B2 @144 -> V @176)
    {
      int j = l;
      const f32x2* wr = (const f32x2*)(ipw + (64 + j) * 32);
      f32x2 accp = f32x2{ipb[64 + j], 0.f};
#pragma unroll
      for (int k2 = 0; k2 < 16; ++k2)
        accp += *(const f32x2*)(S + 144 + 2 * k2) * wr[k2];
      S[176 + j] = accp.x + accp.y;
    }
    __threadfence_block();
    __builtin_amdgcn_wave_barrier();

    // a_mean = opw @ v + opb
    {
      int j = l;
      const f32x2* wr = (const f32x2*)(opw + j * 32);
      f32x2 accp = f32x2{opb[j], 0.f};
#pragma unroll
      for (int k2 = 0; k2 < 16; ++k2)
        accp += *(const f32x2*)(S + 176 + 2 * k2) * wr[k2];
      out[(size_t)s * 96 + 32 + j] = accp.x + accp.y;
    }

    // xf = relu(t[:, :8] @ fc_w.T + fc_b)
    {
      int j = l;
      const f32x2* wr = (const f32x2*)(fcw + j * 8);
      f32x2 accp = f32x2{fcb[j], 0.f};
#pragma unroll
      for (int k2 = 0; k2 < 4; ++k2) {
        f32x2 tv = f32x2{(float)tr[2 * k2], (float)tr[2 * k2 + 1]};
        accp += tv * wr[k2];
      }
      out[(size_t)s * 96 + j] = fmaxf(accp.x + accp.y, 0.f);
    }
  }
}

extern "C" void kernel_launch(void* const* d_in, const int* in_sizes, int n_in,
                              void* d_out, int out_size, void* d_ws, size_t ws_size,
                              hipStream_t stream) {
  const int*   t   = (const int*)d_in[0];
  const int*   pt  = (const int*)d_in[1];
  const float* w1  = (const float*)d_in[2];
  const float* b1  = (const float*)d_in[3];
  const float* w2  = (const float*)d_in[4];
  const float* b2w = (const float*)d_in[5];
  const float* w3  = (const float*)d_in[6];
  const float* b3  = (const float*)d_in[7];
  const float* wf1 = (const float*)d_in[8];
  const float* bf1 = (const float*)d_in[9];
  const float* fcw = (const float*)d_in[10];
  const float* fcb = (const float*)d_in[11];
  // d_in[12] = emb : dead (softmax over singleton axis == 1)
  const float* ipw = (const float*)d_in[13];
  const float* ipb = (const float*)d_in[14];
  const float* opw = (const float*)d_in[15];
  const float* opb = (const float*)d_in[16];

  float* out       = (float*)d_out;
  float* out_board = out + (size_t)BATCH * 96;
  float* ws        = (float*)d_ws;     // 1734 floats

  hipLaunchKernelGGL(precomp_kernel, dim3(7), dim3(256), 0, stream, w1, ws);
  hipLaunchKernelGGL(board_model_kernel, dim3(NBLK), dim3(256), 0, stream,
                     t, pt, w1, b1, w2, b2w, w3, b3, wf1, bf1, fcw, fcb,
                     ipw, ipb, opw, opb, ws, out, out_board);
}